// Round 1
// baseline (112.836 us; speedup 1.0000x reference)
//
#include <hip/hip_runtime.h>
#include <math.h>

#define NB 8
#define ND 128
#define NT 2048
#define NF 1025
#define NYY 256
#define NXX 256
#define NPART 4

// workspace layout (bytes)
#define SCALE_OFF 0
#define PART_OFF  1024
#define SPEC_OFF  4096
#define SPEC_BYTES 8396800   /* 8*128*1025*8 */
#define SF_OFF    (SPEC_OFF + SPEC_BYTES)
// total: SF_OFF + SPEC_BYTES = 16,797,696 bytes (~16.8 MB)

// ---------------- kernel 1a: per-chunk sums for standardization ----------------
__global__ __launch_bounds__(256) void fk_part_sums(const float* __restrict__ sino,
                                                    double2* __restrict__ part) {
  const int c = blockIdx.x;   // 0..31 chunk
  const int b = blockIdx.y;   // 0..7 batch
  const int tid = threadIdx.x;
  const int chunk = ND * NT / 32;  // 8192
  const float* p = sino + (size_t)b * ND * NT + (size_t)c * chunk;
  double s = 0.0, ss = 0.0;
  for (int i = tid; i < chunk; i += 256) {
    float v = p[i];
    s += (double)v;
    ss += (double)v * (double)v;
  }
  __shared__ double shs[256];
  __shared__ double shq[256];
  shs[tid] = s; shq[tid] = ss;
  __syncthreads();
  for (int o = 128; o > 0; o >>= 1) {
    if (tid < o) { shs[tid] += shs[tid + o]; shq[tid] += shq[tid + o]; }
    __syncthreads();
  }
  if (tid == 0) part[b * 32 + c] = make_double2(shs[0], shq[0]);
}

// ---------------- kernel 1b: finalize 1/sqrt(var+eps) ----------------
__global__ void fk_scale_k(const double2* __restrict__ part, float* __restrict__ scale) {
  int t = threadIdx.x;
  if (t < NB) {
    double s = 0.0, ss = 0.0;
    for (int c = 0; c < 32; ++c) { double2 v = part[t * 32 + c]; s += v.x; ss += v.y; }
    const double n = (double)(ND * NT);
    double mean = s / n;
    double var = ss / n - mean * mean;
    scale[t] = (float)(1.0 / sqrt(var + 1.1920928955078125e-7));
  }
}

// ---------------- kernel 2: time FFT (2048-pt, Stockham radix-2) per (b,d) row ----------------
__global__ __launch_bounds__(256) void fk_tfft(const float* __restrict__ sino,
                                               float2* __restrict__ specT) {
  const int row = blockIdx.x;      // b*ND + d
  const int d = row & (ND - 1);
  const int tid = threadIdx.x;
  __shared__ float2 bufA[NT];
  __shared__ float2 bufB[NT];
  // Hann apod (matches numpy: 0.5 - 0.5*cos(2*pi*n/127), computed f64 -> f32)
  const float ap = (float)(0.5 - 0.5 * cos(6.283185307179586 * (double)d / 127.0));
  const float* in = sino + (size_t)row * NT;
  for (int i = tid; i < NT; i += 256) bufA[i] = make_float2(in[i] * ap, 0.0f);
  __syncthreads();
  float2* src = bufA;
  float2* dst = bufB;
  for (int p = 1; p <= NT / 2; p <<= 1) {
    for (int it = 0; it < NT / 2 / 256; ++it) {
      int i = tid + it * 256;
      int k = i & (p - 1);
      float2 u = src[i];
      float2 v = src[i + NT / 2];
      float ang = -3.14159265358979323846f * ((float)k / (float)p);  // k/p exact dyadic
      float sn, cs; __sincosf(ang, &sn, &cs);
      float2 vw = make_float2(v.x * cs - v.y * sn, v.x * sn + v.y * cs);
      int j = ((i - k) << 1) + k;
      dst[j]     = make_float2(u.x + vw.x, u.y + vw.y);
      dst[j + p] = make_float2(u.x - vw.x, u.y - vw.y);
    }
    __syncthreads();
    float2* t = src; src = dst; dst = t;
  }
  float2* out = specT + (size_t)row * NF;
  for (int f = tid; f < NF; f += 256) out[f] = src[f];
}

// ---------------- kernel 3: detector FFT (128-pt) + prop_mask*fw ----------------
__global__ __launch_bounds__(256) void fk_dfft(const float2* __restrict__ specT,
                                               float2* __restrict__ sf) {
  const int b = blockIdx.y;
  const int f0 = blockIdx.x * 4;
  const int sub = threadIdx.x >> 6;   // 0..3 (which f)
  const int i = threadIdx.x & 63;     // butterfly index
  const int f = f0 + sub;
  const bool valid = (f < NF);
  __shared__ float2 A[4][128];
  __shared__ float2 Bf[4][128];
  if (valid) {
    const float2* col = specT + ((size_t)b * ND) * NF + f;
    A[sub][i]      = col[(size_t)i * NF];
    A[sub][i + 64] = col[(size_t)(i + 64) * NF];
  }
  __syncthreads();
  float2 (*src)[128] = A;
  float2 (*dst)[128] = Bf;
  for (int p = 1; p <= 64; p <<= 1) {
    if (valid) {
      int k = i & (p - 1);
      float2 u = src[sub][i];
      float2 v = src[sub][i + 64];
      float ang = -3.14159265358979323846f * ((float)k / (float)p);
      float sn, cs; __sincosf(ang, &sn, &cs);
      float2 vw = make_float2(v.x * cs - v.y * sn, v.x * sn + v.y * cs);
      int j = ((i - k) << 1) + k;
      dst[sub][j]     = make_float2(u.x + vw.x, u.y + vw.y);
      dst[sub][j + p] = make_float2(u.x - vw.x, u.y - vw.y);
    }
    __syncthreads();
    float2 (*t)[128] = src; src = dst; dst = t;
  }
  if (valid) {
    const float fwv = (f == 0 || f == NF - 1) ? 1.0f : 2.0f;
    // replicate reference fp32 ops exactly (no fma contraction)
    double freqd = (double)f / 5.12e-5;                       // == numpy rfftfreq bit-exact
    float omega = (float)(freqd * 6.283185307179586);
    float woc = omega / 1540.0f;
    float woc2 = __fmul_rn(woc, woc);
    #pragma unroll
    for (int h = 0; h < 2; ++h) {
      int kd = i + h * 64;
      int kt = kd < 64 ? kd : kd - 128;
      float kxv = (float)(6.283185307179586 * ((double)kt / 0.0384));
      float kzsq = __fsub_rn(woc2, __fmul_rn(kxv, kxv));
      float m = (kzsq > 0.0f) ? fwv : 0.0f;
      float2 v = src[sub][kd];
      sf[((size_t)(b * ND + kd)) * NF + f] = make_float2(v.x * m, v.y * m);
    }
  }
}

// ---------------- kernel 4: band[b,y,d] = sum_f sf[b,d,f] * exp(i*kz*y) ----------------
__global__ __launch_bounds__(256) void fk_band(const float2* __restrict__ sf,
                                               float2* __restrict__ band) {
  const int d = blockIdx.x;        // 0..127
  const int part = blockIdx.y;     // 0..3
  const int f0 = part * 257;
  const int flen = min(257, NF - f0);
  const int y = threadIdx.x;       // 0..255
  __shared__ float2 sfs[NB][257];
  __shared__ float  kzs[257];
  // stage sf (coalesced) and kz for this d / f-range
  #pragma unroll
  for (int b = 0; b < NB; ++b)
    for (int ff = y; ff < flen; ff += 256)
      sfs[b][ff] = sf[((size_t)(b * ND + d)) * NF + f0 + ff];
  {
    int kt = d < 64 ? d : d - 128;
    float kxv = (float)(6.283185307179586 * ((double)kt / 0.0384));
    float kx2 = __fmul_rn(kxv, kxv);
    for (int ff = y; ff < flen; ff += 256) {
      int f = f0 + ff;
      double freqd = (double)f / 5.12e-5;
      float omega = (float)(freqd * 6.283185307179586);
      float woc = omega / 1540.0f;
      float kzsq = __fsub_rn(__fmul_rn(woc, woc), kx2);
      kzs[ff] = (kzsq > 0.0f) ? sqrtf(kzsq) : 0.0f;
    }
  }
  __syncthreads();
  const float yv = (float)(1.0e-3 + (double)y * 1.5e-4);
  float2 acc[NB];
  #pragma unroll
  for (int b = 0; b < NB; ++b) acc[b] = make_float2(0.0f, 0.0f);
  for (int ff = 0; ff < flen; ++ff) {
    float ang = kzs[ff] * yv;
    float sn, cs; __sincosf(ang, &sn, &cs);
    #pragma unroll
    for (int b = 0; b < NB; ++b) {
      float2 v = sfs[b][ff];   // wave-uniform broadcast
      acc[b].x = fmaf(v.x, cs, fmaf(-v.y, sn, acc[b].x));
      acc[b].y = fmaf(v.x, sn, fmaf( v.y, cs, acc[b].y));
    }
  }
  #pragma unroll
  for (int b = 0; b < NB; ++b)
    band[(((size_t)(part * NB + b)) * NYY + y) * ND + d] = acc[b];
}

// ---------------- kernel 5: lateral inverse DFT + magnitude ----------------
__global__ __launch_bounds__(256) void fk_img(const float2* __restrict__ band,
                                              const float* __restrict__ scale,
                                              float* __restrict__ out, float inv_norm) {
  const int y = blockIdx.x;
  const int b = blockIdx.y;
  const int tid = threadIdx.x;
  __shared__ float2 bs[ND];
  __shared__ float2 tab[NXX];
  {
    float ang = (float)(6.283185307179586 * (double)tid / 256.0);
    float sn, cs; __sincosf(ang, &sn, &cs);
    tab[tid] = make_float2(cs, sn);
  }
  if (tid < ND) {
    float2 s = make_float2(0.0f, 0.0f);
    #pragma unroll
    for (int part = 0; part < NPART; ++part) {
      float2 v = band[(((size_t)(part * NB + b)) * NYY + y) * ND + tid];
      s.x += v.x; s.y += v.y;
    }
    bs[tid] = s;
  }
  __syncthreads();
  const int x = tid;
  float2 acc = make_float2(0.0f, 0.0f);
  for (int d = 0; d < ND; ++d) {
    int md = d < 64 ? d : d + 128;           // signed freq mod 256
    float2 w = tab[(md * x) & 255];
    float2 v = bs[d];                         // broadcast
    acc.x = fmaf(v.x, w.x, fmaf(-v.y, w.y, acc.x));
    acc.y = fmaf(v.x, w.y, fmaf( v.y, w.x, acc.y));
  }
  float mag = sqrtf(acc.x * acc.x + acc.y * acc.y);
  out[((size_t)b * NYY + y) * NXX + x] = mag * scale[b] * inv_norm;
}

extern "C" void kernel_launch(void* const* d_in, const int* in_sizes, int n_in,
                              void* d_out, int out_size, void* d_ws, size_t ws_size,
                              hipStream_t stream) {
  const float* sino = (const float*)d_in[0];
  float* out = (float*)d_out;
  char* ws = (char*)d_ws;

  float*   scale = (float*)(ws + SCALE_OFF);
  double2* part  = (double2*)(ws + PART_OFF);
  float2*  specT = (float2*)(ws + SPEC_OFF);
  float2*  band  = specT;                    // alias: specT fully consumed by fk_dfft
  float2*  sf    = (float2*)(ws + SF_OFF);

  // host-side norm constant: 1 / (sum(hann) * sum(fw)); fw_sum = 1 + 2*1023 + 1 = 2048
  double apod_sum = 0.0;
  for (int n = 0; n < ND; ++n) apod_sum += 0.5 - 0.5 * cos(6.283185307179586 * (double)n / 127.0);
  const float inv_norm = (float)(1.0 / (apod_sum * 2048.0));

  fk_part_sums<<<dim3(32, NB), 256, 0, stream>>>(sino, part);
  fk_scale_k <<<1, 64, 0, stream>>>(part, scale);
  fk_tfft    <<<NB * ND, 256, 0, stream>>>(sino, specT);
  fk_dfft    <<<dim3((NF + 3) / 4, NB), 256, 0, stream>>>(specT, sf);
  fk_band    <<<dim3(ND, NPART), 256, 0, stream>>>(sf, band);
  fk_img     <<<dim3(NYY, NB), 256, 0, stream>>>(band, scale, out, inv_norm);
}

// Round 2
// 107.974 us; speedup vs baseline: 1.0450x; 1.0450x over previous
//
#include <hip/hip_runtime.h>
#include <math.h>

#define NB 8
#define ND 128
#define NT 2048
#define NF 1025
#define NYY 256
#define NXX 256
#define NPART 4

// workspace layout (bytes)
#define SCALE_OFF 0
#define PART_OFF  1024
#define SPEC_OFF  4096
#define SPEC_BYTES 8396800   /* 8*128*1025*8 */
#define SF_OFF    (SPEC_OFF + SPEC_BYTES)
// total: SF_OFF + SPEC_BYTES = 16,797,696 bytes (~16.8 MB)

// ---------------- kernel 1a: per-chunk sums for standardization ----------------
__global__ __launch_bounds__(256) void fk_part_sums(const float* __restrict__ sino,
                                                    double2* __restrict__ part) {
  const int c = blockIdx.x;   // 0..31 chunk
  const int b = blockIdx.y;   // 0..7 batch
  const int tid = threadIdx.x;
  const int chunk = ND * NT / 32;  // 8192
  const float* p = sino + (size_t)b * ND * NT + (size_t)c * chunk;
  double s = 0.0, ss = 0.0;
  for (int i = tid; i < chunk; i += 256) {
    float v = p[i];
    s += (double)v;
    ss += (double)v * (double)v;
  }
  __shared__ double shs[256];
  __shared__ double shq[256];
  shs[tid] = s; shq[tid] = ss;
  __syncthreads();
  for (int o = 128; o > 0; o >>= 1) {
    if (tid < o) { shs[tid] += shs[tid + o]; shq[tid] += shq[tid + o]; }
    __syncthreads();
  }
  if (tid == 0) part[b * 32 + c] = make_double2(shs[0], shq[0]);
}

// ---------------- kernel 1b: finalize 1/sqrt(var+eps) ----------------
__global__ void fk_scale_k(const double2* __restrict__ part, float* __restrict__ scale) {
  int t = threadIdx.x;
  if (t < NB) {
    double s = 0.0, ss = 0.0;
    for (int c = 0; c < 32; ++c) { double2 v = part[t * 32 + c]; s += v.x; ss += v.y; }
    const double n = (double)(ND * NT);
    double mean = s / n;
    double var = ss / n - mean * mean;
    scale[t] = (float)(1.0 / sqrt(var + 1.1920928955078125e-7));
  }
}

// ---------------- kernel 2: time FFT (2048-pt, Stockham radix-2) per (b,d) row ----------------
__global__ __launch_bounds__(256) void fk_tfft(const float* __restrict__ sino,
                                               float2* __restrict__ specT) {
  const int row = blockIdx.x;      // b*ND + d
  const int d = row & (ND - 1);
  const int tid = threadIdx.x;
  __shared__ float2 bufA[NT];
  __shared__ float2 bufB[NT];
  // Hann apod (matches numpy: 0.5 - 0.5*cos(2*pi*n/127), computed f64 -> f32)
  const float ap = (float)(0.5 - 0.5 * cos(6.283185307179586 * (double)d / 127.0));
  const float* in = sino + (size_t)row * NT;
  for (int i = tid; i < NT; i += 256) bufA[i] = make_float2(in[i] * ap, 0.0f);
  __syncthreads();
  float2* src = bufA;
  float2* dst = bufB;
  for (int p = 1; p <= NT / 2; p <<= 1) {
    for (int it = 0; it < NT / 2 / 256; ++it) {
      int i = tid + it * 256;
      int k = i & (p - 1);
      float2 u = src[i];
      float2 v = src[i + NT / 2];
      float ang = -3.14159265358979323846f * ((float)k / (float)p);  // k/p exact dyadic
      float sn, cs; __sincosf(ang, &sn, &cs);
      float2 vw = make_float2(v.x * cs - v.y * sn, v.x * sn + v.y * cs);
      int j = ((i - k) << 1) + k;
      dst[j]     = make_float2(u.x + vw.x, u.y + vw.y);
      dst[j + p] = make_float2(u.x - vw.x, u.y - vw.y);
    }
    __syncthreads();
    float2* t = src; src = dst; dst = t;
  }
  float2* out = specT + (size_t)row * NF;
  for (int f = tid; f < NF; f += 256) out[f] = src[f];
}

// ---------------- kernel 3: detector FFT (128-pt) + prop_mask*fw ----------------
__global__ __launch_bounds__(256) void fk_dfft(const float2* __restrict__ specT,
                                               float2* __restrict__ sf) {
  const int b = blockIdx.y;
  const int f0 = blockIdx.x * 4;
  const int sub = threadIdx.x >> 6;   // 0..3 (which f)
  const int i = threadIdx.x & 63;     // butterfly index
  const int f = f0 + sub;
  const bool valid = (f < NF);
  __shared__ float2 A[4][128];
  __shared__ float2 Bf[4][128];
  if (valid) {
    const float2* col = specT + ((size_t)b * ND) * NF + f;
    A[sub][i]      = col[(size_t)i * NF];
    A[sub][i + 64] = col[(size_t)(i + 64) * NF];
  }
  __syncthreads();
  float2 (*src)[128] = A;
  float2 (*dst)[128] = Bf;
  for (int p = 1; p <= 64; p <<= 1) {
    if (valid) {
      int k = i & (p - 1);
      float2 u = src[sub][i];
      float2 v = src[sub][i + 64];
      float ang = -3.14159265358979323846f * ((float)k / (float)p);
      float sn, cs; __sincosf(ang, &sn, &cs);
      float2 vw = make_float2(v.x * cs - v.y * sn, v.x * sn + v.y * cs);
      int j = ((i - k) << 1) + k;
      dst[sub][j]     = make_float2(u.x + vw.x, u.y + vw.y);
      dst[sub][j + p] = make_float2(u.x - vw.x, u.y - vw.y);
    }
    __syncthreads();
    float2 (*t)[128] = src; src = dst; dst = t;
  }
  if (valid) {
    const float fwv = (f == 0 || f == NF - 1) ? 1.0f : 2.0f;
    // replicate reference fp32 ops exactly (no fma contraction)
    double freqd = (double)f / 5.12e-5;                       // == numpy rfftfreq bit-exact
    float omega = (float)(freqd * 6.283185307179586);
    float woc = omega / 1540.0f;
    float woc2 = __fmul_rn(woc, woc);
    #pragma unroll
    for (int h = 0; h < 2; ++h) {
      int kd = i + h * 64;
      int kt = kd < 64 ? kd : kd - 128;
      float kxv = (float)(6.283185307179586 * ((double)kt / 0.0384));
      float kzsq = __fsub_rn(woc2, __fmul_rn(kxv, kxv));
      float m = (kzsq > 0.0f) ? fwv : 0.0f;
      float2 v = src[sub][kd];
      sf[((size_t)(b * ND + kd)) * NF + f] = make_float2(v.x * m, v.y * m);
    }
  }
}

// ---------------- kernel 4: band[b,y,d] = sum_f sf[b,d,f] * exp(i*kz*y) ----------------
// kz symmetry: kz[d] == kz[128-d]  (kx^2 even), so one sincos feeds two d's.
// grid: (dg 0..64, part 0..3, bgroup 0..3); each block: 2 batches x {d, 128-d}
__global__ __launch_bounds__(256) void fk_band(const float2* __restrict__ sf,
                                               float2* __restrict__ band) {
  const int dg   = blockIdx.x;       // 0..64
  const int part = blockIdx.y;       // 0..3
  const int bg   = blockIdx.z;       // 0..3
  const int b0   = bg * 2;
  const int d0   = dg;
  const int d1   = 128 - dg;         // invalid (128) when dg==0; dup when dg==64
  const bool single = (dg == 0) || (dg == 64);
  const int f0 = part * 257;
  const int flen = min(257, NF - f0);
  const int y = threadIdx.x;         // 0..255

  __shared__ float2 sfs[257][4];     // [ff][{d0b0, d0b1, d1b0, d1b1}]
  __shared__ float  kzs[257];

  for (int ff = y; ff < flen; ff += 256) {
    const int f = f0 + ff;
    sfs[ff][0] = sf[((size_t)(b0 * ND + d0)) * NF + f];
    sfs[ff][1] = sf[((size_t)((b0 + 1) * ND + d0)) * NF + f];
    if (!single) {
      sfs[ff][2] = sf[((size_t)(b0 * ND + d1)) * NF + f];
      sfs[ff][3] = sf[((size_t)((b0 + 1) * ND + d1)) * NF + f];
    } else {
      sfs[ff][2] = make_float2(0.0f, 0.0f);
      sfs[ff][3] = make_float2(0.0f, 0.0f);
    }
    // kz from d0 (kt in 0..64; (-64)^2 == 64^2 exactly, matches reference)
    float kxv = (float)(6.283185307179586 * ((double)d0 / 0.0384));
    float kx2 = __fmul_rn(kxv, kxv);
    double freqd = (double)f / 5.12e-5;
    float omega = (float)(freqd * 6.283185307179586);
    float woc = omega / 1540.0f;
    float kzsq = __fsub_rn(__fmul_rn(woc, woc), kx2);
    kzs[ff] = (kzsq > 0.0f) ? sqrtf(kzsq) : 0.0f;
  }
  __syncthreads();

  const float yv = (float)(1.0e-3 + (double)y * 1.5e-4);
  float2 a00 = make_float2(0.f, 0.f), a01 = make_float2(0.f, 0.f);
  float2 a10 = make_float2(0.f, 0.f), a11 = make_float2(0.f, 0.f);
  for (int ff = 0; ff < flen; ++ff) {
    float ang = kzs[ff] * yv;
    float sn, cs; __sincosf(ang, &sn, &cs);
    float4 p0 = *(const float4*)&sfs[ff][0];   // (d0,b0) (d0,b1)
    float4 p1 = *(const float4*)&sfs[ff][2];   // (d1,b0) (d1,b1)
    a00.x = fmaf(p0.x, cs, fmaf(-p0.y, sn, a00.x));
    a00.y = fmaf(p0.x, sn, fmaf( p0.y, cs, a00.y));
    a01.x = fmaf(p0.z, cs, fmaf(-p0.w, sn, a01.x));
    a01.y = fmaf(p0.z, sn, fmaf( p0.w, cs, a01.y));
    a10.x = fmaf(p1.x, cs, fmaf(-p1.y, sn, a10.x));
    a10.y = fmaf(p1.x, sn, fmaf( p1.y, cs, a10.y));
    a11.x = fmaf(p1.z, cs, fmaf(-p1.w, sn, a11.x));
    a11.y = fmaf(p1.z, sn, fmaf( p1.w, cs, a11.y));
  }
  band[(((size_t)(part * NB + b0    )) * NYY + y) * ND + d0] = a00;
  band[(((size_t)(part * NB + b0 + 1)) * NYY + y) * ND + d0] = a01;
  if (!single) {
    band[(((size_t)(part * NB + b0    )) * NYY + y) * ND + d1] = a10;
    band[(((size_t)(part * NB + b0 + 1)) * NYY + y) * ND + d1] = a11;
  }
}

// ---------------- kernel 5: lateral inverse DFT + magnitude ----------------
// per-thread twiddle recurrence: w_d = exp(i*2pi*md*x/256), md = d (d<64) else d+128
__global__ __launch_bounds__(256) void fk_img(const float2* __restrict__ band,
                                              const float* __restrict__ scale,
                                              float* __restrict__ out, float inv_norm) {
  const int y = blockIdx.x;
  const int b = blockIdx.y;
  const int tid = threadIdx.x;
  __shared__ float2 bs[ND];
  if (tid < ND) {
    float2 s = make_float2(0.0f, 0.0f);
    #pragma unroll
    for (int part = 0; part < NPART; ++part) {
      float2 v = band[(((size_t)(part * NB + b)) * NYY + y) * ND + tid];
      s.x += v.x; s.y += v.y;
    }
    bs[tid] = s;
  }
  __syncthreads();
  const int x = tid;
  float ang = (float)(6.283185307179586 * (double)x / 256.0);
  float sn, cs; __sincosf(ang, &sn, &cs);
  const float2 step = make_float2(cs, sn);
  float2 w = make_float2(1.0f, 0.0f);
  float2 acc = make_float2(0.0f, 0.0f);
  #pragma unroll 4
  for (int d = 0; d < 64; ++d) {
    float2 v = bs[d];                       // broadcast
    acc.x = fmaf(v.x, w.x, fmaf(-v.y, w.y, acc.x));
    acc.y = fmaf(v.x, w.y, fmaf( v.y, w.x, acc.y));
    float2 nw;
    nw.x = fmaf(w.x, step.x, -w.y * step.y);
    nw.y = fmaf(w.x, step.y,  w.y * step.x);
    w = nw;
  }
  // frequency wrap: d=64 needs step^192 = step^64 * step^128, step^128 = (-1)^x
  if (x & 1) { w.x = -w.x; w.y = -w.y; }
  #pragma unroll 4
  for (int d = 64; d < 128; ++d) {
    float2 v = bs[d];
    acc.x = fmaf(v.x, w.x, fmaf(-v.y, w.y, acc.x));
    acc.y = fmaf(v.x, w.y, fmaf( v.y, w.x, acc.y));
    float2 nw;
    nw.x = fmaf(w.x, step.x, -w.y * step.y);
    nw.y = fmaf(w.x, step.y,  w.y * step.x);
    w = nw;
  }
  float mag = sqrtf(acc.x * acc.x + acc.y * acc.y);
  out[((size_t)b * NYY + y) * NXX + x] = mag * scale[b] * inv_norm;
}

extern "C" void kernel_launch(void* const* d_in, const int* in_sizes, int n_in,
                              void* d_out, int out_size, void* d_ws, size_t ws_size,
                              hipStream_t stream) {
  const float* sino = (const float*)d_in[0];
  float* out = (float*)d_out;
  char* ws = (char*)d_ws;

  float*   scale = (float*)(ws + SCALE_OFF);
  double2* part  = (double2*)(ws + PART_OFF);
  float2*  specT = (float2*)(ws + SPEC_OFF);
  float2*  band  = specT;                    // alias: specT fully consumed by fk_dfft
  float2*  sf    = (float2*)(ws + SF_OFF);

  // host-side norm constant: 1 / (sum(hann) * sum(fw)); fw_sum = 1 + 2*1023 + 1 = 2048
  double apod_sum = 0.0;
  for (int n = 0; n < ND; ++n) apod_sum += 0.5 - 0.5 * cos(6.283185307179586 * (double)n / 127.0);
  const float inv_norm = (float)(1.0 / (apod_sum * 2048.0));

  fk_part_sums<<<dim3(32, NB), 256, 0, stream>>>(sino, part);
  fk_scale_k <<<1, 64, 0, stream>>>(part, scale);
  fk_tfft    <<<NB * ND, 256, 0, stream>>>(sino, specT);
  fk_dfft    <<<dim3((NF + 3) / 4, NB), 256, 0, stream>>>(specT, sf);
  fk_band    <<<dim3(65, NPART, 4), 256, 0, stream>>>(sf, band);
  fk_img     <<<dim3(NYY, NB), 256, 0, stream>>>(band, scale, out, inv_norm);
}